// Round 11
// baseline (23.694 us; speedup 1.0000x reference)
//
#include <hip/hip_runtime.h>
#include <math.h>

#define ATOMS 200

static __device__ __forceinline__ float3 f3(float x, float y, float z) {
    return make_float3(x, y, z);
}
static __device__ __forceinline__ float3 sub3(float3 a, float3 b) {
    return f3(a.x - b.x, a.y - b.y, a.z - b.z);
}
static __device__ __forceinline__ float dot3(float3 a, float3 b) {
    return fmaf(a.x, b.x, fmaf(a.y, b.y, a.z * b.z));
}
static __device__ __forceinline__ float3 cross3(float3 a, float3 b) {
    return f3(fmaf(a.y, b.z, -a.z * b.y),
              fmaf(a.z, b.x, -a.x * b.z),
              fmaf(a.x, b.y, -a.y * b.x));
}

// two consecutive atoms (24B) in one packed load -> dwordx4 + dwordx2
struct __attribute__((packed, aligned(4))) f6 { float v[6]; };

// asin via A&S 4.4.45: abs err <= 6.8e-5 rad (threshold is 2e-2), ~8 VALU + 1 trans
static __device__ __forceinline__ float asin_fast(float x) {
    float a = fminf(fabsf(x), 1.0f);
    float t = __builtin_amdgcn_sqrtf(1.0f - a);
    float p = fmaf(a, -0.0187293f, 0.0742610f);
    p = fmaf(a, p, -0.2121144f);
    p = fmaf(a, p, 1.5707288f);
    return copysignf(fmaf(-t, p, 1.5707963267948966f), x);
}

// base(i) = number of (i',j) pairs with i' < i (row i has m-i entries)
static __device__ __forceinline__ int row_base(int i, int m) {
    return i * m - (i * (i - 1)) / 2;
}

// Thread-per-element. Rationale (R10 post-mortem): chunked rolling saved
// ~25% of math but its register pressure + serial carry chain held issue
// utilization at ~34% (21.6us vs 7.2us issue floor). Thread-per-element at
// low VGPR demonstrably runs ~92% VALUBusy (R3 profile) — higher raw FLOPs,
// lower wall clock.
__global__ __launch_bounds__(256) void writhe_kernel(
    const float* __restrict__ xyz,
    float*       __restrict__ out,
    int S, int m /* = A-3 */)
{
    const int s = blockIdx.x * blockDim.x + threadIdx.x;
    if (s >= S) return;
    const int f = blockIdx.y;

    // branchless s -> (i, j): i = floor((2m+1 - sqrt((2m+1)^2 - 8s))/2),
    // disc < 2^24 so fp32 is exact up to 0.5 ulp; +-1 fixup via flat selects
    const float tm = 2.0f * (float)m + 1.0f;
    const float disc = fmaf(tm, tm, -8.0f * (float)s);
    int i = (int)(0.5f * (tm - __builtin_amdgcn_sqrtf(disc)));
    i = max(0, min(i, m - 1));
    i += (int)(i < m - 1 && row_base(i + 1, m) <= s);
    i += (int)(i < m - 1 && row_base(i + 1, m) <= s);
    i -= (int)(i > 0 && row_base(i, m) > s);
    const int j = i + 2 + (s - row_base(i, m));

    const float* __restrict__ fx = xyz + (size_t)f * (ATOMS * 3);
    const f6 A = *reinterpret_cast<const f6*>(fx + 3 * i);  // atoms i, i+1
    const f6 B = *reinterpret_cast<const f6*>(fx + 3 * j);  // atoms j, j+1

    const float3 p0 = f3(A.v[0], A.v[1], A.v[2]);
    const float3 p1 = f3(A.v[3], A.v[4], A.v[5]);
    const float3 p2 = f3(B.v[0], B.v[1], B.v[2]);
    const float3 p3 = f3(B.v[3], B.v[4], B.v[5]);

    // unnormalized displacements (normalization provably cancels)
    const float3 d0 = sub3(p2, p0), d1 = sub3(p3, p0);
    const float3 d2 = sub3(p2, p1), d3 = sub3(p3, p1);

    // crosses (c2 never needed: ref's dots[2] = c2.c2 = 1 -> constant pi/2)
    const float3 u0 = cross3(d0, d1);
    const float3 u1 = cross3(d1, d3);
    const float3 u3 = cross3(d2, d0);

    const float n0 = dot3(u0, u0);
    const float n1 = dot3(u1, u1);
    const float n3 = dot3(u3, u3);

    const float d01 = dot3(u0, u1) * __builtin_amdgcn_rsqf(n0 * n1);
    const float d13 = dot3(u1, u3) * __builtin_amdgcn_rsqf(n1 * n3);
    const float d30 = dot3(u3, u0) * __builtin_amdgcn_rsqf(n3 * n0);

    const float half_pi = 1.5707963267948966f;
    const float inv2pi  = 0.15915494309189535f;
    const float omega = asin_fast(d01) + asin_fast(d13) + asin_fast(d30) + half_pi;

    // sign( ((p3-p2) x (p1-p0)) . d0 ) == sign(-u0.d2);  r *= sign(sv)
    // multiply-by-(+-1) == sign-bit XOR (exact); zero when sv == 0
    const float sv = -dot3(u0, d2);
    float r = omega * inv2pi;
    const unsigned rb = __float_as_uint(r) ^ (__float_as_uint(sv) & 0x80000000u);
    r = (sv == 0.0f) ? 0.0f : __uint_as_float(rb);

    out[(size_t)f * S + s] = r;
}

extern "C" void kernel_launch(void* const* d_in, const int* in_sizes, int n_in,
                              void* d_out, int out_size, void* d_ws, size_t ws_size,
                              hipStream_t stream)
{
    const float* xyz = (const float*)d_in[0];
    float*       out = (float*)d_out;

    const int F = in_sizes[0] / (ATOMS * 3);
    const int S = out_size / F;              // = (A-2)(A-3)/2
    const int m = (int)((-1.0 + sqrt(1.0 + 8.0 * (double)S)) * 0.5 + 0.5);

    dim3 grid((S + 255) / 256, F);
    writhe_kernel<<<grid, 256, 0, stream>>>(xyz, out, S, m);
}